// Round 1
// baseline (32.582 us; speedup 1.0000x reference)
//
#include <hip/hip_runtime.h>

// Problem: N=8192, d_model=2048, h=16, d_k=128.
// Key simplification: softmax over a size-1 axis == 1.0 exactly, so
//   head_out[h,n,:] = v_proj[h,0,:]  (independent of n, and of q/Wq/Wk).
// Output = broadcast of (vp @ Wo) where vp[h*128+k] = sum_d v_param[d]*Wv[h,d,k].

#define NROWS 8192
#define DM    2048
#define H     16
#define DK    128
#define NCH   32     // chunks over d (2048/64)
#define DCH   64

// K1: partial v-projection. grid (32 chunks, 16 heads), 128 threads (k).
// part1[c][h*128+k] = sum_{d in chunk c} v_param[d] * Wv[h,d,k]
__global__ __launch_bounds__(128) void k_vproj(const float* __restrict__ Wv,
                                               const float* __restrict__ vparam,
                                               float* __restrict__ part1) {
    const int c = blockIdx.x;   // 0..31
    const int h = blockIdx.y;   // 0..15
    const int k = threadIdx.x;  // 0..127
    const float* wp = Wv + (size_t)h * DM * DK + (size_t)c * DCH * DK + k;
    const float* vq = vparam + c * DCH;
    float acc = 0.f;
#pragma unroll 8
    for (int d = 0; d < DCH; ++d) {
        acc += vq[d] * wp[(size_t)d * DK];
    }
    part1[c * (H * DK) + h * DK + k] = acc;
}

// K2: partial output-row projection. grid (8 m-blocks, 32 j-chunks), 256 thr.
// First deterministically reduce part1 over chunks for this block's 64 j's,
// then part2[jc][m] = sum_{j in jc} vp[j] * Wo[j,m]
__global__ __launch_bounds__(256) void k_rowproj(const float* __restrict__ part1,
                                                 const float* __restrict__ Wo,
                                                 float* __restrict__ part2) {
    const int mb = blockIdx.x;  // 0..7
    const int jc = blockIdx.y;  // 0..31
    const int t  = threadIdx.x; // 0..255
    __shared__ float vp[64];
    if (t < 64) {
        const int j = jc * 64 + t;
        float s = 0.f;
#pragma unroll
        for (int c = 0; c < NCH; ++c) s += part1[c * DM + j];
        vp[t] = s;
    }
    __syncthreads();
    const int m = mb * 256 + t;
    const float* wo = Wo + (size_t)(jc * 64) * DM + m;
    float acc = 0.f;
#pragma unroll 8
    for (int jj = 0; jj < 64; ++jj) acc += vp[jj] * wo[(size_t)jj * DM];
    part2[jc * DM + m] = acc;
}

// K3: reduce part2 over j-chunks -> full 2048-float row in LDS, then
// broadcast-store to 16 output rows per block. grid 512, 256 threads.
__global__ __launch_bounds__(256) void k_bcast(const float* __restrict__ part2,
                                               float* __restrict__ out) {
    __shared__ float row[DM];
    const int t  = threadIdx.x;
    const int bg = blockIdx.x;  // 0..511, 16 rows each
#pragma unroll
    for (int i = 0; i < 8; ++i) {
        const int m = i * 256 + t;
        float s = 0.f;
#pragma unroll
        for (int c = 0; c < NCH; ++c) s += part2[c * DM + m];
        row[m] = s;
    }
    __syncthreads();
    const float4 f0 = ((const float4*)row)[t];
    const float4 f1 = ((const float4*)row)[256 + t];
    float4* out4 = (float4*)out;
    const size_t base = (size_t)bg * 16 * (DM / 4);
#pragma unroll
    for (int n = 0; n < 16; ++n) {
        out4[base + (size_t)n * (DM / 4) + t]       = f0;
        out4[base + (size_t)n * (DM / 4) + 256 + t] = f1;
    }
}

extern "C" void kernel_launch(void* const* d_in, const int* in_sizes, int n_in,
                              void* d_out, int out_size, void* d_ws, size_t ws_size,
                              hipStream_t stream) {
    // inputs: 0=q, 1=Wq, 2=Wk, 3=Wv, 4=k_param, 5=v_param, 6=Wo (all fp32)
    const float* Wv     = (const float*)d_in[3];
    const float* vparam = (const float*)d_in[5];
    const float* Wo     = (const float*)d_in[6];
    float* out = (float*)d_out;

    float* part1 = (float*)d_ws;           // 32*2048 floats = 256 KB
    float* part2 = part1 + NCH * DM;       // 32*2048 floats = 256 KB

    k_vproj  <<<dim3(NCH, H), 128, 0, stream>>>(Wv, vparam, part1);
    k_rowproj<<<dim3(8, NCH), 256, 0, stream>>>(part1, Wo, part2);
    k_bcast  <<<512, 256, 0, stream>>>(part2, out);
}

// Round 2
// 29.688 us; speedup vs baseline: 1.0975x; 1.0975x over previous
//
#include <hip/hip_runtime.h>

// Problem: N=8192, d_model=2048, h=16, d_k=128.
// softmax over a size-1 axis == 1.0 exactly, so
//   head_out[h,n,:] = v_proj[h,0,:]  (independent of n, and of q/Wq/Wk).
// Output = broadcast of (vp @ Wo) where vp[h*128+k] = sum_d v_param[d]*Wv[h,d,k].
//
// K1: part1[c][j]   = partial vp over d-chunk c            (reads Wv, 16 MB)
// K2: part2[jc][m]  = sum_{j in jc} vp[j]*Wo[j,m]          (reads Wo, 16 MB)
// K3: out[n][m]     = sum_jc part2[jc][m], broadcast rows  (writes 64 MB)

#define NROWS 8192
#define DM    2048
#define H     16
#define DK    128
#define NCH   32     // chunks over d (2048/64)
#define DCH   64

// K1: grid (32 d-chunks, 16 heads), 128 threads (k).
__global__ __launch_bounds__(128) void k_vproj(const float* __restrict__ Wv,
                                               const float* __restrict__ vparam,
                                               float* __restrict__ part1) {
    const int c = blockIdx.x;   // 0..31
    const int h = blockIdx.y;   // 0..15
    const int k = threadIdx.x;  // 0..127
    const float* wp = Wv + (size_t)h * DM * DK + (size_t)c * DCH * DK + k;
    const float* vq = vparam + c * DCH;
    float acc = 0.f;
#pragma unroll 8
    for (int d = 0; d < DCH; ++d) {
        acc += vq[d] * wp[(size_t)d * DK];
    }
    part1[c * (H * DK) + h * DK + k] = acc;
}

// K2: grid (8 m-blocks of 256, 32 j-chunks of 64), 256 threads.
// Reduce part1 over chunks for this block's 64 j's, then partial row proj.
__global__ __launch_bounds__(256) void k_rowproj(const float* __restrict__ part1,
                                                 const float* __restrict__ Wo,
                                                 float* __restrict__ part2) {
    const int mb = blockIdx.x;  // 0..7
    const int jc = blockIdx.y;  // 0..31
    const int t  = threadIdx.x; // 0..255
    __shared__ float vp[64];
    if (t < 64) {
        const int j = jc * 64 + t;
        float s = 0.f;
#pragma unroll
        for (int c = 0; c < NCH; ++c) s += part1[c * DM + j];
        vp[t] = s;
    }
    __syncthreads();
    const int m = mb * 256 + t;
    const float* wo = Wo + (size_t)(jc * 64) * DM + m;
    float acc = 0.f;
#pragma unroll 8
    for (int jj = 0; jj < 64; ++jj) acc += vp[jj] * wo[(size_t)jj * DM];
    part2[jc * DM + m] = acc;
}

// K3: pure register reduce + broadcast store. No LDS, no barrier.
// grid (2 col-halves of 1024 floats, 256 row-groups of 32 rows), 256 threads.
// Each thread: float4 acc over 32 chunks (coalesced L2 reads), then store
// its float4 to 32 output rows (4 KB contiguous per row per block).
__global__ __launch_bounds__(256) void k_bcast(const float* __restrict__ part2,
                                               float* __restrict__ out) {
    const int cs = blockIdx.x;  // 0..1  (column half)
    const int rg = blockIdx.y;  // 0..255 (row group of 32)
    const int t  = threadIdx.x; // 0..255
    const float4* p4 = (const float4*)(part2) + cs * 256 + t;  // part2[c][cs*1024 + 4t]
    float4 acc = {0.f, 0.f, 0.f, 0.f};
#pragma unroll
    for (int c = 0; c < NCH; ++c) {
        const float4 v = p4[c * (DM / 4)];
        acc.x += v.x; acc.y += v.y; acc.z += v.z; acc.w += v.w;
    }
    float4* out4 = (float4*)out + (size_t)(rg * 32) * (DM / 4) + cs * 256 + t;
#pragma unroll
    for (int r = 0; r < 32; ++r) {
        out4[(size_t)r * (DM / 4)] = acc;
    }
}

extern "C" void kernel_launch(void* const* d_in, const int* in_sizes, int n_in,
                              void* d_out, int out_size, void* d_ws, size_t ws_size,
                              hipStream_t stream) {
    // inputs: 0=q, 1=Wq, 2=Wk, 3=Wv, 4=k_param, 5=v_param, 6=Wo (all fp32)
    const float* Wv     = (const float*)d_in[3];
    const float* vparam = (const float*)d_in[5];
    const float* Wo     = (const float*)d_in[6];
    float* out = (float*)d_out;

    float* part1 = (float*)d_ws;           // 32*2048 floats = 256 KB
    float* part2 = part1 + NCH * DM;       // 32*2048 floats = 256 KB

    k_vproj  <<<dim3(NCH, H), 128, 0, stream>>>(Wv, vparam, part1);
    k_rowproj<<<dim3(8, NCH), 256, 0, stream>>>(part1, Wo, part2);
    k_bcast  <<<dim3(2, 256), 256, 0, stream>>>(part2, out);
}